// Round 6
// baseline (277.103 us; speedup 1.0000x reference)
//
#include <hip/hip_runtime.h>
#include <math.h>

#define DDIM 4096
#define NTOK 8192

typedef float nfloat4 __attribute__((ext_vector_type(4)));

__device__ __forceinline__ float softplus_f(float r) {
  return (r > 0.0f) ? (r + log1pf(__expf(-r))) : log1pf(__expf(r));
}

// gt in NATURAL order: this layout never permutes elements, so the main
// kernel consumes g_tilde with the same coalesced float4 pattern as x.
__global__ __launch_bounds__(256) void gt_kernel(
    const float* __restrict__ g_mu, const float* __restrict__ g_rho,
    const float* __restrict__ eps, float* __restrict__ gt)
{
  int i = blockIdx.x * 256 + threadIdx.x;   // 0..4095
  gt[i] = g_mu[i] + softplus_f(g_rho[i]) * eps[i];
}

// ---- cross-lane butterfly helpers ------------------------------------------
// x' = fma(x, sgn, partner): bit==0 lanes compute a+b, bit==1 lanes p-x.
__device__ __forceinline__ float bfly_dpp_x1(float x, float sgn) {
  // quad_perm [1,0,3,2] = 0xB1 -> partner lane^1 (pure VALU)
  float p = __int_as_float(__builtin_amdgcn_mov_dpp(__float_as_int(x), 0xB1, 0xF, 0xF, true));
  return fmaf(x, sgn, p);
}
__device__ __forceinline__ float bfly_dpp_x2(float x, float sgn) {
  // quad_perm [2,3,0,1] = 0x4E -> partner lane^2 (pure VALU)
  float p = __int_as_float(__builtin_amdgcn_mov_dpp(__float_as_int(x), 0x4E, 0xF, 0xF, true));
  return fmaf(x, sgn, p);
}
__device__ __forceinline__ float bfly_sw_x4(float x, float sgn) {
  // ds_swizzle BitMode: (xor<<10)|(or<<5)|and ; xor=4, and=0x1F
  float p = __int_as_float(__builtin_amdgcn_ds_swizzle(__float_as_int(x), 0x101F));
  return fmaf(x, sgn, p);
}
__device__ __forceinline__ float bfly_dpp_x8(float x, float sgn) {
  // row_ror:8 (0x128): within a 16-lane row, rotate-by-8 == lane^8 (pure VALU)
  float p = __int_as_float(__builtin_amdgcn_mov_dpp(__float_as_int(x), 0x128, 0xF, 0xF, true));
  return fmaf(x, sgn, p);
}
__device__ __forceinline__ float bfly_sw_x16(float x, float sgn) {
  // BitMode xor=16 within each 32-lane half: 0x401F
  float p = __int_as_float(__builtin_amdgcn_ds_swizzle(__float_as_int(x), 0x401F));
  return fmaf(x, sgn, p);
}
__device__ __forceinline__ float bfly_shfl_x32(float x, float sgn) {
  // lane^32 crosses the 32-lane swizzle boundary -> shfl_xor (bpermute/permlane)
  float p = __shfl_xor(x, 32, 64);
  return fmaf(x, sgn, p);
}

// 6-bit FWHT over the 64 per-lane registers (index bits {11,10,9,8,1,0}).
__device__ __forceinline__ void fwht64reg(float w[64]) {
#pragma unroll
  for (int m = 1; m < 64; m <<= 1) {
#pragma unroll
    for (int k = 0; k < 64; ++k) {
      if ((k & m) == 0) {
        float a = w[k], b = w[k ^ m];
        w[k]     = a + b;
        w[k ^ m] = a - b;
      }
    }
  }
}

// FWHT over the 6 lane bits (= element bits i[7:2]). DS stages issued first
// within each pair so their latency overlaps the pure-VALU DPP stages.
__device__ __forceinline__ void fwht_lane6(float w[64], float sg1, float sg2,
                                           float sg4, float sg8, float sg16,
                                           float sg32) {
#pragma unroll
  for (int k = 0; k < 64; ++k) w[k] = bfly_sw_x4(w[k], sg4);
#pragma unroll
  for (int k = 0; k < 64; ++k) w[k] = bfly_dpp_x1(w[k], sg1);
#pragma unroll
  for (int k = 0; k < 64; ++k) w[k] = bfly_dpp_x2(w[k], sg2);
#pragma unroll
  for (int k = 0; k < 64; ++k) w[k] = bfly_sw_x16(w[k], sg16);
#pragma unroll
  for (int k = 0; k < 64; ++k) w[k] = bfly_dpp_x8(w[k], sg8);
#pragma unroll
  for (int k = 0; k < 64; ++k) w[k] = bfly_shfl_x32(w[k], sg32);
}

// ---------------------------------------------------------------------------
// One row per 64-thread block (ONE wave), 64 floats/lane. Element mapping is
// fixed for the whole kernel: i = 256*(u>>2) + 4*t + (u&3)  (t=lane, u=reg).
// Reg bits u = {i11,i10,i9,i8,i1,i0}; lane bits t = i[7:2]. The full 4096-pt
// FWHT = fwht64reg (6 reg bits) + fwht_lane6 (6 lane bits via DPP/swizzle/
// shfl). NO LDS buffer, NO __syncthreads — waves are fully independent, so
// latency hiding is pure TLP with zero correlated barrier stalls (R3/R5
// showed the 4-wave barrier structure pinned all pipes at ~33%).
// x, gt, s1, s2 all stream with the identical coalesced float4 pattern;
// s1/s2/gt are L1-hot after the first row on each CU.
// VGPR ~90 expected -> 4 waves/SIMD (16 waves/CU). No launch_bounds min-waves
// clause (R4: it forces spills; R5: 76 VGPR is past the 64 cliff anyway).
// ---------------------------------------------------------------------------
template <bool USE_WS>
__global__ __launch_bounds__(64) void whvi_kernel(
    const float* __restrict__ x,
    const float* __restrict__ s1v,
    const float* __restrict__ s2v,
    const float* __restrict__ gt,        // USE_WS path (natural order)
    const float* __restrict__ g_mu,      // fallback path
    const float* __restrict__ g_rho,
    const float* __restrict__ eps,
    float* __restrict__ out)
{
  const int t = threadIdx.x;              // 0..63
  const size_t row = (size_t)blockIdx.x;

  const float sg1  = (t & 1)  ? -1.0f : 1.0f;
  const float sg2  = (t & 2)  ? -1.0f : 1.0f;
  const float sg4  = (t & 4)  ? -1.0f : 1.0f;
  const float sg8  = (t & 8)  ? -1.0f : 1.0f;
  const float sg16 = (t & 16) ? -1.0f : 1.0f;
  const float sg32 = (t & 32) ? -1.0f : 1.0f;

  float w[64];

  // ---- load x row (16x b128, coalesced) and multiply by s2 (L1-hot) ----
  const float4* x4  = (const float4*)x + row * (DDIM / 4);
  const float4* s24 = (const float4*)s2v;
#pragma unroll
  for (int j = 0; j < 16; ++j) {
    float4 a = x4[64 * j + t];
    float4 b = s24[64 * j + t];
    w[4 * j + 0] = a.x * b.x;
    w[4 * j + 1] = a.y * b.y;
    w[4 * j + 2] = a.z * b.z;
    w[4 * j + 3] = a.w * b.w;
  }

  // ---- FWHT pass 1 (all 12 bits, no layout change) ----
  fwht64reg(w);
  fwht_lane6(w, sg1, sg2, sg4, sg8, sg16, sg32);

  // ---- multiply by g_tilde (natural order, same coalesced pattern) ----
  if (USE_WS) {
    const float4* g4 = (const float4*)gt;
#pragma unroll
    for (int j = 0; j < 16; ++j) {
      float4 g = g4[64 * j + t];
      w[4 * j + 0] *= g.x;
      w[4 * j + 1] *= g.y;
      w[4 * j + 2] *= g.z;
      w[4 * j + 3] *= g.w;
    }
  } else {
    const float4* m4 = (const float4*)g_mu;
    const float4* r4 = (const float4*)g_rho;
    const float4* e4 = (const float4*)eps;
#pragma unroll
    for (int j = 0; j < 16; ++j) {
      float4 m = m4[64 * j + t];
      float4 rr = r4[64 * j + t];
      float4 e = e4[64 * j + t];
      w[4 * j + 0] *= m.x + softplus_f(rr.x) * e.x;
      w[4 * j + 1] *= m.y + softplus_f(rr.y) * e.y;
      w[4 * j + 2] *= m.z + softplus_f(rr.z) * e.z;
      w[4 * j + 3] *= m.w + softplus_f(rr.w) * e.w;
    }
  }

  // ---- FWHT pass 2 ----
  fwht64reg(w);
  fwht_lane6(w, sg1, sg2, sg4, sg8, sg16, sg32);

  // ---- multiply by s1, nt-store (bypass L3: keep x resident) ----
  const float4* s14 = (const float4*)s1v;
  float4* out4 = (float4*)out + row * (DDIM / 4);
#pragma unroll
  for (int j = 0; j < 16; ++j) {
    float4 b = s14[64 * j + t];
    nfloat4 v = { w[4 * j + 0] * b.x, w[4 * j + 1] * b.y,
                  w[4 * j + 2] * b.z, w[4 * j + 3] * b.w };
    __builtin_nontemporal_store(v, (nfloat4*)&out4[64 * j + t]);
  }
}

extern "C" void kernel_launch(void* const* d_in, const int* in_sizes, int n_in,
                              void* d_out, int out_size, void* d_ws, size_t ws_size,
                              hipStream_t stream) {
  const float* x     = (const float*)d_in[0];
  const float* s1    = (const float*)d_in[1];
  const float* s2    = (const float*)d_in[2];
  const float* g_mu  = (const float*)d_in[3];
  const float* g_rho = (const float*)d_in[4];
  const float* eps   = (const float*)d_in[5];
  float* out = (float*)d_out;

  if (ws_size >= DDIM * sizeof(float)) {
    float* gt = (float*)d_ws;
    gt_kernel<<<DDIM / 256, 256, 0, stream>>>(g_mu, g_rho, eps, gt);
    whvi_kernel<true><<<NTOK, 64, 0, stream>>>(
        x, s1, s2, gt, nullptr, nullptr, nullptr, out);
  } else {
    whvi_kernel<false><<<NTOK, 64, 0, stream>>>(
        x, s1, s2, nullptr, g_mu, g_rho, eps, out);
  }
}

// Round 8
// 275.726 us; speedup vs baseline: 1.0050x; 1.0050x over previous
//
#include <hip/hip_runtime.h>
#include <math.h>

#define DDIM 4096
#define NTOK 8192
#define WPB 4             // independent waves (rows) per 256-thread workgroup

typedef float nfloat4 __attribute__((ext_vector_type(4)));

__device__ __forceinline__ float softplus_f(float r) {
  return (r > 0.0f) ? (r + log1pf(__expf(-r))) : log1pf(__expf(r));
}

// gt in NATURAL order: this layout never permutes elements, so the main
// kernel consumes g_tilde with the same coalesced float4 pattern as x.
__global__ __launch_bounds__(256) void gt_kernel(
    const float* __restrict__ g_mu, const float* __restrict__ g_rho,
    const float* __restrict__ eps, float* __restrict__ gt)
{
  int i = blockIdx.x * 256 + threadIdx.x;   // 0..4095
  gt[i] = g_mu[i] + softplus_f(g_rho[i]) * eps[i];
}

// ---- cross-lane butterfly helpers ------------------------------------------
// x' = fma(x, sgn, partner): bit==0 lanes compute a+b, bit==1 lanes p-x.
__device__ __forceinline__ float bfly_dpp_x1(float x, float sgn) {
  // quad_perm [1,0,3,2] = 0xB1 -> partner lane^1 (pure VALU)
  float p = __int_as_float(__builtin_amdgcn_mov_dpp(__float_as_int(x), 0xB1, 0xF, 0xF, true));
  return fmaf(x, sgn, p);
}
__device__ __forceinline__ float bfly_dpp_x2(float x, float sgn) {
  // quad_perm [2,3,0,1] = 0x4E -> partner lane^2 (pure VALU)
  float p = __int_as_float(__builtin_amdgcn_mov_dpp(__float_as_int(x), 0x4E, 0xF, 0xF, true));
  return fmaf(x, sgn, p);
}
__device__ __forceinline__ float bfly_sw_x4(float x, float sgn) {
  // ds_swizzle BitMode: (xor<<10)|(or<<5)|and ; xor=4, and=0x1F
  float p = __int_as_float(__builtin_amdgcn_ds_swizzle(__float_as_int(x), 0x101F));
  return fmaf(x, sgn, p);
}
__device__ __forceinline__ float bfly_dpp_x8(float x, float sgn) {
  // row_ror:8 (0x128): within a 16-lane row, rotate-by-8 == lane^8 (pure VALU)
  float p = __int_as_float(__builtin_amdgcn_mov_dpp(__float_as_int(x), 0x128, 0xF, 0xF, true));
  return fmaf(x, sgn, p);
}
__device__ __forceinline__ float bfly_sw_x16(float x, float sgn) {
  // BitMode xor=16 within each 32-lane half: 0x401F
  float p = __int_as_float(__builtin_amdgcn_ds_swizzle(__float_as_int(x), 0x401F));
  return fmaf(x, sgn, p);
}
__device__ __forceinline__ float bfly_shfl_x32(float x, float sgn) {
  // lane^32: __shfl_xor (ds_bpermute) — PROVEN correct in R6. R7's
  // permlane32_swap substitution broke correctness (absmax 10.2); reverted.
  float p = __shfl_xor(x, 32, 64);
  return fmaf(x, sgn, p);
}

// 6-bit FWHT over the 64 per-lane registers (index bits {11,10,9,8,1,0}).
__device__ __forceinline__ void fwht64reg(float w[64]) {
#pragma unroll
  for (int m = 1; m < 64; m <<= 1) {
#pragma unroll
    for (int k = 0; k < 64; ++k) {
      if ((k & m) == 0) {
        float a = w[k], b = w[k ^ m];
        w[k]     = a + b;
        w[k ^ m] = a - b;
      }
    }
  }
}

// FWHT over the 6 lane bits (= element bits i[7:2]). DS stages (x4, x16,
// x32) interleave with pure-VALU DPP stages (x1, x2, x8).
__device__ __forceinline__ void fwht_lane6(float w[64], float sg1, float sg2,
                                           float sg4, float sg8, float sg16,
                                           float sg32) {
#pragma unroll
  for (int k = 0; k < 64; ++k) w[k] = bfly_sw_x4(w[k], sg4);
#pragma unroll
  for (int k = 0; k < 64; ++k) w[k] = bfly_dpp_x1(w[k], sg1);
#pragma unroll
  for (int k = 0; k < 64; ++k) w[k] = bfly_dpp_x2(w[k], sg2);
#pragma unroll
  for (int k = 0; k < 64; ++k) w[k] = bfly_sw_x16(w[k], sg16);
#pragma unroll
  for (int k = 0; k < 64; ++k) w[k] = bfly_dpp_x8(w[k], sg8);
#pragma unroll
  for (int k = 0; k < 64; ++k) w[k] = bfly_shfl_x32(w[k], sg32);
}

// ---------------------------------------------------------------------------
// WPB independent rows per 256-thread workgroup — one row per WAVE, 64
// floats/lane. The workgroup is purely a residency container: zero LDS,
// zero __syncthreads (R0/R6 evidence: single-wave workgroups cap at ~6
// resident waves/CU; 4-wave workgroups reached ~24). Element mapping fixed:
// i = 256*(u>>2) + 4*t + (u&3)  (t=lane, u=reg). Reg bits {11,10,9,8,1,0}
// via fwht64reg; lane bits i[7:2] via DPP/swizzle/shfl.
// x, gt, s1, s2 all stream with the identical coalesced float4 pattern.
// ---------------------------------------------------------------------------
template <bool USE_WS>
__global__ __launch_bounds__(256) void whvi_kernel(
    const float* __restrict__ x,
    const float* __restrict__ s1v,
    const float* __restrict__ s2v,
    const float* __restrict__ gt,        // USE_WS path (natural order)
    const float* __restrict__ g_mu,      // fallback path
    const float* __restrict__ g_rho,
    const float* __restrict__ eps,
    float* __restrict__ out)
{
  const int t = threadIdx.x & 63;               // lane within wave
  const size_t row = (size_t)blockIdx.x * WPB + (threadIdx.x >> 6);

  const float sg1  = (t & 1)  ? -1.0f : 1.0f;
  const float sg2  = (t & 2)  ? -1.0f : 1.0f;
  const float sg4  = (t & 4)  ? -1.0f : 1.0f;
  const float sg8  = (t & 8)  ? -1.0f : 1.0f;
  const float sg16 = (t & 16) ? -1.0f : 1.0f;
  const float sg32 = (t & 32) ? -1.0f : 1.0f;

  float w[64];

  // ---- load x row (16x b128, coalesced) and multiply by s2 (L1-hot) ----
  const float4* x4  = (const float4*)x + row * (DDIM / 4);
  const float4* s24 = (const float4*)s2v;
#pragma unroll
  for (int j = 0; j < 16; ++j) {
    float4 a = x4[64 * j + t];
    float4 b = s24[64 * j + t];
    w[4 * j + 0] = a.x * b.x;
    w[4 * j + 1] = a.y * b.y;
    w[4 * j + 2] = a.z * b.z;
    w[4 * j + 3] = a.w * b.w;
  }

  // ---- FWHT pass 1 (all 12 bits, no layout change) ----
  fwht64reg(w);
  fwht_lane6(w, sg1, sg2, sg4, sg8, sg16, sg32);

  // ---- multiply by g_tilde (natural order, same coalesced pattern) ----
  if (USE_WS) {
    const float4* g4 = (const float4*)gt;
#pragma unroll
    for (int j = 0; j < 16; ++j) {
      float4 g = g4[64 * j + t];
      w[4 * j + 0] *= g.x;
      w[4 * j + 1] *= g.y;
      w[4 * j + 2] *= g.z;
      w[4 * j + 3] *= g.w;
    }
  } else {
    const float4* m4 = (const float4*)g_mu;
    const float4* r4 = (const float4*)g_rho;
    const float4* e4 = (const float4*)eps;
#pragma unroll
    for (int j = 0; j < 16; ++j) {
      float4 m = m4[64 * j + t];
      float4 rr = r4[64 * j + t];
      float4 e = e4[64 * j + t];
      w[4 * j + 0] *= m.x + softplus_f(rr.x) * e.x;
      w[4 * j + 1] *= m.y + softplus_f(rr.y) * e.y;
      w[4 * j + 2] *= m.z + softplus_f(rr.z) * e.z;
      w[4 * j + 3] *= m.w + softplus_f(rr.w) * e.w;
    }
  }

  // ---- FWHT pass 2 ----
  fwht64reg(w);
  fwht_lane6(w, sg1, sg2, sg4, sg8, sg16, sg32);

  // ---- multiply by s1, nt-store (bypass L3: keep x resident) ----
  const float4* s14 = (const float4*)s1v;
  float4* out4 = (float4*)out + row * (DDIM / 4);
#pragma unroll
  for (int j = 0; j < 16; ++j) {
    float4 b = s14[64 * j + t];
    nfloat4 v = { w[4 * j + 0] * b.x, w[4 * j + 1] * b.y,
                  w[4 * j + 2] * b.z, w[4 * j + 3] * b.w };
    __builtin_nontemporal_store(v, (nfloat4*)&out4[64 * j + t]);
  }
}

extern "C" void kernel_launch(void* const* d_in, const int* in_sizes, int n_in,
                              void* d_out, int out_size, void* d_ws, size_t ws_size,
                              hipStream_t stream) {
  const float* x     = (const float*)d_in[0];
  const float* s1    = (const float*)d_in[1];
  const float* s2    = (const float*)d_in[2];
  const float* g_mu  = (const float*)d_in[3];
  const float* g_rho = (const float*)d_in[4];
  const float* eps   = (const float*)d_in[5];
  float* out = (float*)d_out;

  if (ws_size >= DDIM * sizeof(float)) {
    float* gt = (float*)d_ws;
    gt_kernel<<<DDIM / 256, 256, 0, stream>>>(g_mu, g_rho, eps, gt);
    whvi_kernel<true><<<NTOK / WPB, 256, 0, stream>>>(
        x, s1, s2, gt, nullptr, nullptr, nullptr, out);
  } else {
    whvi_kernel<false><<<NTOK / WPB, 256, 0, stream>>>(
        x, s1, s2, nullptr, g_mu, g_rho, eps, out);
  }
}

// Round 9
// 270.111 us; speedup vs baseline: 1.0259x; 1.0208x over previous
//
#include <hip/hip_runtime.h>
#include <math.h>

#define DDIM 4096
#define NTOK 8192
#define WPB 2             // waves (rows) per workgroup; LDS = WPB*16KB

typedef float nfloat4 __attribute__((ext_vector_type(4)));

__device__ __forceinline__ float softplus_f(float r) {
  return (r > 0.0f) ? (r + log1pf(__expf(-r))) : log1pf(__expf(r));
}

// ---------------------------------------------------------------------------
// Element-index maps.
// Layout A (load/store): lane t, reg u=4j+r  ->  i = 256*j + 4*t + r
//   reg bits {i11..i8, i1, i0}, lane bits t = i[7:2].
// Mid layout (after exchange-1): lane bits {i4,i6,i7} swapped with reg bits
//   {i8,i9,i10}:  i = r | t0<<2 | t1<<3 | j0<<4 | t3<<5 | j1<<6 | j2<<7
//                     | t5<<8 | t4<<9 | t2<<10 | j3<<11
// g_tilde is consumed in MID layout; gt_perm[s=256j+4t+r] = g_tilde[i(t,j,r)]
// so the main kernel's float4 g-loads are perfectly coalesced.
// ---------------------------------------------------------------------------
__device__ __forceinline__ int mid_lane_part(int t) {
  return ((t & 1) << 2) | (((t >> 1) & 1) << 3) | (((t >> 3) & 1) << 5) |
         (((t >> 5) & 1) << 8) | (((t >> 4) & 1) << 9) | (((t >> 2) & 1) << 10);
}
__device__ __forceinline__ constexpr int mid_j_part(int j) {
  return ((j & 1) << 4) | (((j >> 1) & 1) << 6) | (((j >> 2) & 1) << 7) |
         (((j >> 3) & 1) << 11);
}

__global__ __launch_bounds__(256) void gt_perm_kernel(
    const float* __restrict__ g_mu, const float* __restrict__ g_rho,
    const float* __restrict__ eps, float* __restrict__ gt_perm)
{
  int s = blockIdx.x * 256 + threadIdx.x;   // 0..4095
  int r = s & 3, t = (s >> 2) & 63, j = s >> 8;
  int i = r + mid_lane_part(t) + mid_j_part(j);
  gt_perm[s] = g_mu[i] + softplus_f(g_rho[i]) * eps[i];
}

// ---- pure-VALU lane butterflies (DPP) --------------------------------------
__device__ __forceinline__ float bfly_dpp_x1(float x, float sgn) {
  float p = __int_as_float(__builtin_amdgcn_mov_dpp(__float_as_int(x), 0xB1, 0xF, 0xF, true));
  return fmaf(x, sgn, p);
}
__device__ __forceinline__ float bfly_dpp_x2(float x, float sgn) {
  float p = __int_as_float(__builtin_amdgcn_mov_dpp(__float_as_int(x), 0x4E, 0xF, 0xF, true));
  return fmaf(x, sgn, p);
}
__device__ __forceinline__ float bfly_dpp_x8(float x, float sgn) {
  // row_ror:8 (0x128): rotate-by-8 within a 16-lane row == lane^8
  float p = __int_as_float(__builtin_amdgcn_mov_dpp(__float_as_int(x), 0x128, 0xF, 0xF, true));
  return fmaf(x, sgn, p);
}

// 6-bit FWHT over the 64 per-lane registers.
__device__ __forceinline__ void fwht64reg(float w[64]) {
#pragma unroll
  for (int m = 1; m < 64; m <<= 1) {
#pragma unroll
    for (int k = 0; k < 64; ++k) {
      if ((k & m) == 0) {
        float a = w[k], b = w[k ^ m];
        w[k]     = a + b;
        w[k ^ m] = a - b;
      }
    }
  }
}

// 3-bit FWHT over reg-bit strides 4, 8, 16 (the bits the exchange brings in).
__device__ __forceinline__ void fwht8reg(float w[64]) {
#pragma unroll
  for (int m = 4; m <= 16; m <<= 1) {
#pragma unroll
    for (int k = 0; k < 64; ++k) {
      if ((k & m) == 0) {
        float a = w[k], b = w[k ^ m];
        w[k]     = a + b;
        w[k ^ m] = a - b;
      }
    }
  }
}

// ---------------------------------------------------------------------------
// One row per WAVE (64 floats/lane), WPB waves per WG, zero __syncthreads:
// each wave owns a private 16KB LDS region used ONLY for two intra-wave b128
// exchanges per row (lgkmcnt-ordered by the compiler, no barrier needed).
// Per FWHT pass: fwht64reg (6 reg bits, VALU) + DPP x1/x2/x8 (lane bits
// i2,i3,i5, VALU) + one LDS exchange swapping lane{i4,i6,i7}<->reg{i8,i9,i10}
// + fwht8reg. Pass 2's exchange swaps back, restoring layout A for the
// coalesced s1-mult + nt-store. DS ops/row: 64 b128 (vs 384 swizzles in R8);
// DS-latency exposures/row: 2 (vs 12). Addresses XOR-swizzled so every b128
// op spreads uniformly (8 dwords/bank = the 1KB/wave64 minimum).
// The pass-loop (#pragma unroll 1) emits the heavy FWHT body once (~13KB vs
// ~22KB straight-line) — I$ insurance for this long unrolled kernel.
// ---------------------------------------------------------------------------
template <bool USE_WS>
__global__ __launch_bounds__(64 * WPB) void whvi_kernel(
    const float* __restrict__ x,
    const float* __restrict__ s1v,
    const float* __restrict__ s2v,
    const float* __restrict__ gt_perm,   // USE_WS path (mid layout)
    const float* __restrict__ g_mu,      // fallback path
    const float* __restrict__ g_rho,
    const float* __restrict__ eps,
    float* __restrict__ out)
{
  __shared__ __align__(16) float L[WPB * DDIM];

  const int t  = threadIdx.x & 63;
  const int wv = threadIdx.x >> 6;
  float* Lw = &L[wv * DDIM];
  const size_t row = (size_t)blockIdx.x * WPB + wv;

  const float sg1 = (t & 1) ? -1.0f : 1.0f;
  const float sg2 = (t & 2) ? -1.0f : 1.0f;
  const float sg8 = (t & 8) ? -1.0f : 1.0f;

  // address lane-parts. Swizzle: XOR addr bits [10:8] into [4:2] (uniform
  // bank spread for both the A-pattern and the mid-pattern accesses).
  const int awl = 4 * t;                       // A layout: addr = 256j+4t (+r), sw-XOR (j&7)<<2
  const int lm  = mid_lane_part(t);            // mid layout element lane part
  const int swx = (((t >> 5) & 1) << 2) | (((t >> 4) & 1) << 3) |
                  (((t >> 2) & 1) << 4);       // mid addr bits[10:8]={t5,t4,t2} -> XOR into [4:2]

  float w[64];

  // ---- load x row (16x b128, coalesced) and multiply by s2 (L1-hot) ----
  const float4* x4  = (const float4*)x + row * (DDIM / 4);
  const float4* s24 = (const float4*)s2v;
#pragma unroll
  for (int j = 0; j < 16; ++j) {
    float4 a = x4[64 * j + t];
    float4 b = s24[64 * j + t];
    w[4 * j + 0] = a.x * b.x;
    w[4 * j + 1] = a.y * b.y;
    w[4 * j + 2] = a.z * b.z;
    w[4 * j + 3] = a.w * b.w;
  }

#pragma unroll 1
  for (int pass = 0; pass < 2; ++pass) {
    // 6 reg bits
    fwht64reg(w);
    // lane bits i2 (x1), i3 (x2), i5 (x8) — pure VALU, identical both passes
#pragma unroll
    for (int k = 0; k < 64; ++k) w[k] = bfly_dpp_x1(w[k], sg1);
#pragma unroll
    for (int k = 0; k < 64; ++k) w[k] = bfly_dpp_x2(w[k], sg2);
#pragma unroll
    for (int k = 0; k < 64; ++k) w[k] = bfly_dpp_x8(w[k], sg8);

    // exchange: swap lane{i4,i6,i7} <-> reg{i8,i9,i10} (intra-wave, no barrier)
    if (pass == 0) {
      // write layout A, read mid
#pragma unroll
      for (int j = 0; j < 16; ++j) {
        int aw = (256 * j + awl) ^ ((j & 7) << 2);
        *(float4*)&Lw[aw] =
            make_float4(w[4 * j + 0], w[4 * j + 1], w[4 * j + 2], w[4 * j + 3]);
      }
#pragma unroll
      for (int j = 0; j < 16; ++j) {
        int ar = (lm + mid_j_part(j)) ^ swx;
        float4 v = *(const float4*)&Lw[ar];
        w[4 * j + 0] = v.x; w[4 * j + 1] = v.y;
        w[4 * j + 2] = v.z; w[4 * j + 3] = v.w;
      }
    } else {
      // write mid, read layout A (restores original layout)
#pragma unroll
      for (int j = 0; j < 16; ++j) {
        int aw = (lm + mid_j_part(j)) ^ swx;
        *(float4*)&Lw[aw] =
            make_float4(w[4 * j + 0], w[4 * j + 1], w[4 * j + 2], w[4 * j + 3]);
      }
#pragma unroll
      for (int j = 0; j < 16; ++j) {
        int ar = (256 * j + awl) ^ ((j & 7) << 2);
        float4 v = *(const float4*)&Lw[ar];
        w[4 * j + 0] = v.x; w[4 * j + 1] = v.y;
        w[4 * j + 2] = v.z; w[4 * j + 3] = v.w;
      }
    }
    // 3 arrived reg bits (pass1: {i4,i6,i7}; pass2: {i8,i9,i10})
    fwht8reg(w);

    if (pass == 0) {
      // ---- multiply by g_tilde in MID layout ----
      if (USE_WS) {
        const float4* g4 = (const float4*)gt_perm;
#pragma unroll
        for (int j = 0; j < 16; ++j) {
          float4 g = g4[64 * j + t];
          w[4 * j + 0] *= g.x;
          w[4 * j + 1] *= g.y;
          w[4 * j + 2] *= g.z;
          w[4 * j + 3] *= g.w;
        }
      } else {
#pragma unroll
        for (int j = 0; j < 16; ++j) {
          int i0 = lm + mid_j_part(j);
#pragma unroll
          for (int r = 0; r < 4; ++r) {
            int i = i0 + r;
            float g = g_mu[i] + softplus_f(g_rho[i]) * eps[i];
            w[4 * j + r] *= g;
          }
        }
      }
    }
  }

  // ---- multiply by s1 (layout A), nt-store (keep x L3-resident) ----
  const float4* s14 = (const float4*)s1v;
  float4* out4 = (float4*)out + row * (DDIM / 4);
#pragma unroll
  for (int j = 0; j < 16; ++j) {
    float4 b = s14[64 * j + t];
    nfloat4 v = { w[4 * j + 0] * b.x, w[4 * j + 1] * b.y,
                  w[4 * j + 2] * b.z, w[4 * j + 3] * b.w };
    __builtin_nontemporal_store(v, (nfloat4*)&out4[64 * j + t]);
  }
}

extern "C" void kernel_launch(void* const* d_in, const int* in_sizes, int n_in,
                              void* d_out, int out_size, void* d_ws, size_t ws_size,
                              hipStream_t stream) {
  const float* x     = (const float*)d_in[0];
  const float* s1    = (const float*)d_in[1];
  const float* s2    = (const float*)d_in[2];
  const float* g_mu  = (const float*)d_in[3];
  const float* g_rho = (const float*)d_in[4];
  const float* eps   = (const float*)d_in[5];
  float* out = (float*)d_out;

  if (ws_size >= DDIM * sizeof(float)) {
    float* gt_perm = (float*)d_ws;
    gt_perm_kernel<<<DDIM / 256, 256, 0, stream>>>(g_mu, g_rho, eps, gt_perm);
    whvi_kernel<true><<<NTOK / WPB, 64 * WPB, 0, stream>>>(
        x, s1, s2, gt_perm, nullptr, nullptr, nullptr, out);
  } else {
    whvi_kernel<false><<<NTOK / WPB, 64 * WPB, 0, stream>>>(
        x, s1, s2, nullptr, g_mu, g_rho, eps, out);
  }
}

// Round 10
// 269.005 us; speedup vs baseline: 1.0301x; 1.0041x over previous
//
#include <hip/hip_runtime.h>
#include <math.h>

#define DDIM 4096
#define NTOK 8192
#define WPB 4             // waves (rows) per workgroup; LDS = WPB * 8KB

typedef float nfloat4 __attribute__((ext_vector_type(4)));

__device__ __forceinline__ float softplus_f(float r) {
  return (r > 0.0f) ? (r + log1pf(__expf(-r))) : log1pf(__expf(r));
}

// ---------------------------------------------------------------------------
// Element-index maps (unchanged from R9).
// Layout A (load/store): lane t, reg u=4j+r  ->  i = 256*j + 4*t + r
//   reg bits {i11..i8, i1, i0}, lane bits t = i[7:2].
// Mid layout (after exchange-1): lane bits {i4,i6,i7} swapped with reg bits
//   {i8,i9,i10}; i11 stays a REG bit in both layouts -> the LDS exchange
//   decomposes into two independent 8KB halves (regs j<8 / j>=8).
// g_tilde is consumed in MID layout; gt_perm[s=256j+4t+r] = g_tilde[i(t,j,r)]
// so the main kernel's float4 g-loads are perfectly coalesced.
// ---------------------------------------------------------------------------
__device__ __forceinline__ int mid_lane_part(int t) {
  return ((t & 1) << 2) | (((t >> 1) & 1) << 3) | (((t >> 3) & 1) << 5) |
         (((t >> 5) & 1) << 8) | (((t >> 4) & 1) << 9) | (((t >> 2) & 1) << 10);
}
__device__ __forceinline__ constexpr int mid_j_part(int j) {      // full (gt/fallback)
  return ((j & 1) << 4) | (((j >> 1) & 1) << 6) | (((j >> 2) & 1) << 7) |
         (((j >> 3) & 1) << 11);
}
__device__ __forceinline__ constexpr int mid_j_lo(int jj) {       // within-half (jj=0..7)
  return ((jj & 1) << 4) | (((jj >> 1) & 1) << 6) | (((jj >> 2) & 1) << 7);
}

__global__ __launch_bounds__(256) void gt_perm_kernel(
    const float* __restrict__ g_mu, const float* __restrict__ g_rho,
    const float* __restrict__ eps, float* __restrict__ gt_perm)
{
  int s = blockIdx.x * 256 + threadIdx.x;   // 0..4095
  int r = s & 3, t = (s >> 2) & 63, j = s >> 8;
  int i = r + mid_lane_part(t) + mid_j_part(j);
  gt_perm[s] = g_mu[i] + softplus_f(g_rho[i]) * eps[i];
}

// ---- pure-VALU lane butterflies (DPP) --------------------------------------
__device__ __forceinline__ float bfly_dpp_x1(float x, float sgn) {
  float p = __int_as_float(__builtin_amdgcn_mov_dpp(__float_as_int(x), 0xB1, 0xF, 0xF, true));
  return fmaf(x, sgn, p);
}
__device__ __forceinline__ float bfly_dpp_x2(float x, float sgn) {
  float p = __int_as_float(__builtin_amdgcn_mov_dpp(__float_as_int(x), 0x4E, 0xF, 0xF, true));
  return fmaf(x, sgn, p);
}
__device__ __forceinline__ float bfly_dpp_x8(float x, float sgn) {
  // row_ror:8 (0x128): rotate-by-8 within a 16-lane row == lane^8
  float p = __int_as_float(__builtin_amdgcn_mov_dpp(__float_as_int(x), 0x128, 0xF, 0xF, true));
  return fmaf(x, sgn, p);
}

// 6-bit FWHT over the 64 per-lane registers.
__device__ __forceinline__ void fwht64reg(float w[64]) {
#pragma unroll
  for (int m = 1; m < 64; m <<= 1) {
#pragma unroll
    for (int k = 0; k < 64; ++k) {
      if ((k & m) == 0) {
        float a = w[k], b = w[k ^ m];
        w[k]     = a + b;
        w[k ^ m] = a - b;
      }
    }
  }
}

// 3-bit FWHT over reg strides 4,8,16 within one 32-reg half (strides stay
// inside the half since 16 < 32).
__device__ __forceinline__ void fwht8half(float* wh) {
#pragma unroll
  for (int m = 4; m <= 16; m <<= 1) {
#pragma unroll
    for (int k = 0; k < 32; ++k) {
      if ((k & m) == 0) {
        float a = wh[k], b = wh[k ^ m];
        wh[k]     = a + b;
        wh[k ^ m] = a - b;
      }
    }
  }
}

// ---------------------------------------------------------------------------
// One row per WAVE (64 floats/lane), WPB waves/WG, zero __syncthreads.
// R10 change vs R9: the per-wave LDS exchange runs as TWO independent 8KB
// half-exchanges (split by reg bit i11, which both layouts keep in regs),
// cutting per-wave LDS 16KB -> 8KB so LDS allows 20 waves/CU instead of 10
// (VGPR 128 then caps at 16/CU = 2-3x R9's measured residency). An explicit
// lgkmcnt(0)+sched_barrier fence between halves guards the 8KB reuse.
// Everything else (DPP lane stages, mid-layout g-mult, nt stores) is R9's
// proven-correct structure.
// ---------------------------------------------------------------------------
template <bool USE_WS>
__global__ __launch_bounds__(256) void whvi_kernel(
    const float* __restrict__ x,
    const float* __restrict__ s1v,
    const float* __restrict__ s2v,
    const float* __restrict__ gt_perm,   // USE_WS path (mid layout)
    const float* __restrict__ g_mu,      // fallback path
    const float* __restrict__ g_rho,
    const float* __restrict__ eps,
    float* __restrict__ out)
{
  __shared__ __align__(16) float L[WPB * 2048];   // 8KB per wave

  const int t  = threadIdx.x & 63;
  const int wv = threadIdx.x >> 6;
  float* Lw = &L[wv * 2048];
  const size_t row = (size_t)blockIdx.x * WPB + wv;

  const float sg1 = (t & 1) ? -1.0f : 1.0f;
  const float sg2 = (t & 2) ? -1.0f : 1.0f;
  const float sg8 = (t & 8) ? -1.0f : 1.0f;

  // address lane-parts + XOR swizzles (same bank-spread scheme as R9,
  // restricted to the 8KB half: addr bits [10:8] XOR'd into [4:2]).
  const int awl = 4 * t;
  const int lm  = mid_lane_part(t);
  const int swx = (((t >> 5) & 1) << 2) | (((t >> 4) & 1) << 3) |
                  (((t >> 2) & 1) << 4);

  float w[64];

  // ---- load x row (16x b128, coalesced) and multiply by s2 (L1-hot) ----
  const float4* x4  = (const float4*)x + row * (DDIM / 4);
  const float4* s24 = (const float4*)s2v;
#pragma unroll
  for (int j = 0; j < 16; ++j) {
    float4 a = x4[64 * j + t];
    float4 b = s24[64 * j + t];
    w[4 * j + 0] = a.x * b.x;
    w[4 * j + 1] = a.y * b.y;
    w[4 * j + 2] = a.z * b.z;
    w[4 * j + 3] = a.w * b.w;
  }

#pragma unroll 1
  for (int pass = 0; pass < 2; ++pass) {
    // 6 reg bits
    fwht64reg(w);
    // lane bits i2 (x1), i3 (x2), i5 (x8) — pure VALU
#pragma unroll
    for (int k = 0; k < 64; ++k) w[k] = bfly_dpp_x1(w[k], sg1);
#pragma unroll
    for (int k = 0; k < 64; ++k) w[k] = bfly_dpp_x2(w[k], sg2);
#pragma unroll
    for (int k = 0; k < 64; ++k) w[k] = bfly_dpp_x8(w[k], sg8);

    // exchange lane{i4,i6,i7} <-> reg{i8,i9,i10}, two 8KB halves (i11 = h)
#pragma unroll
    for (int h = 0; h < 2; ++h) {
      float* wh = &w[32 * h];
      if (pass == 0) {
        // write layout A (local), read mid (local)
#pragma unroll
        for (int jj = 0; jj < 8; ++jj) {
          int aw = (256 * jj + awl) ^ (jj << 2);
          *(float4*)&Lw[aw] =
              make_float4(wh[4 * jj + 0], wh[4 * jj + 1], wh[4 * jj + 2], wh[4 * jj + 3]);
        }
#pragma unroll
        for (int jj = 0; jj < 8; ++jj) {
          int ar = (lm + mid_j_lo(jj)) ^ swx;
          float4 v = *(const float4*)&Lw[ar];
          wh[4 * jj + 0] = v.x; wh[4 * jj + 1] = v.y;
          wh[4 * jj + 2] = v.z; wh[4 * jj + 3] = v.w;
        }
      } else {
        // write mid (local), read layout A (local) -> restores layout A
#pragma unroll
        for (int jj = 0; jj < 8; ++jj) {
          int aw = (lm + mid_j_lo(jj)) ^ swx;
          *(float4*)&Lw[aw] =
              make_float4(wh[4 * jj + 0], wh[4 * jj + 1], wh[4 * jj + 2], wh[4 * jj + 3]);
        }
#pragma unroll
        for (int jj = 0; jj < 8; ++jj) {
          int ar = (256 * jj + awl) ^ (jj << 2);
          float4 v = *(const float4*)&Lw[ar];
          wh[4 * jj + 0] = v.x; wh[4 * jj + 1] = v.y;
          wh[4 * jj + 2] = v.z; wh[4 * jj + 3] = v.w;
        }
      }
      // 3 arrived reg bits within this half (pass0: {i4,i6,i7}; pass1: {i8,i9,i10})
      fwht8half(wh);
      if (h == 0) {
        // drain half-0's reads before half-1 overwrites the 8KB region
        asm volatile("s_waitcnt lgkmcnt(0)" ::: "memory");
        __builtin_amdgcn_sched_barrier(0);
      }
    }

    if (pass == 0) {
      // ---- multiply by g_tilde in MID layout ----
      if (USE_WS) {
        const float4* g4 = (const float4*)gt_perm;
#pragma unroll
        for (int j = 0; j < 16; ++j) {
          float4 g = g4[64 * j + t];
          w[4 * j + 0] *= g.x;
          w[4 * j + 1] *= g.y;
          w[4 * j + 2] *= g.z;
          w[4 * j + 3] *= g.w;
        }
      } else {
#pragma unroll
        for (int j = 0; j < 16; ++j) {
          int i0 = lm + mid_j_part(j);
#pragma unroll
          for (int r = 0; r < 4; ++r) {
            int i = i0 + r;
            float g = g_mu[i] + softplus_f(g_rho[i]) * eps[i];
            w[4 * j + r] *= g;
          }
        }
      }
    }
  }

  // ---- multiply by s1 (layout A), nt-store (keep x L3-resident) ----
  const float4* s14 = (const float4*)s1v;
  float4* out4 = (float4*)out + row * (DDIM / 4);
#pragma unroll
  for (int j = 0; j < 16; ++j) {
    float4 b = s14[64 * j + t];
    nfloat4 v = { w[4 * j + 0] * b.x, w[4 * j + 1] * b.y,
                  w[4 * j + 2] * b.z, w[4 * j + 3] * b.w };
    __builtin_nontemporal_store(v, (nfloat4*)&out4[64 * j + t]);
  }
}

extern "C" void kernel_launch(void* const* d_in, const int* in_sizes, int n_in,
                              void* d_out, int out_size, void* d_ws, size_t ws_size,
                              hipStream_t stream) {
  const float* x     = (const float*)d_in[0];
  const float* s1    = (const float*)d_in[1];
  const float* s2    = (const float*)d_in[2];
  const float* g_mu  = (const float*)d_in[3];
  const float* g_rho = (const float*)d_in[4];
  const float* eps   = (const float*)d_in[5];
  float* out = (float*)d_out;

  if (ws_size >= DDIM * sizeof(float)) {
    float* gt_perm = (float*)d_ws;
    gt_perm_kernel<<<DDIM / 256, 256, 0, stream>>>(g_mu, g_rho, eps, gt_perm);
    whvi_kernel<true><<<NTOK / WPB, 256, 0, stream>>>(
        x, s1, s2, gt_perm, nullptr, nullptr, nullptr, out);
  } else {
    whvi_kernel<false><<<NTOK / WPB, 256, 0, stream>>>(
        x, s1, s2, nullptr, g_mu, g_rho, eps, out);
  }
}